// Round 4
// baseline (433.388 us; speedup 1.0000x reference)
//
#include <hip/hip_runtime.h>
#include <hip/hip_bf16.h>
#include <cstdint>
#include <math.h>

// Problem constants
#define S_LEN   2048
#define B_SZ    2
#define D_MODEL 2048
#define NH      16
#define NKV     4
#define HD      128
#define ROWS    (S_LEN * B_SZ)          // 4096
#define NQKV    3072                    // NH*HD + 2*NKV*HD
#define SCALE   0.08838834764831845f    // 1/sqrt(HD)

typedef __attribute__((ext_vector_type(8))) short short8;   // 8 bf16 = 4 VGPRs
typedef __attribute__((ext_vector_type(4))) float f32x4;    // MFMA acc

__device__ __forceinline__ short f2bf(float f) {
  union { float f; unsigned u; } v; v.f = f;
  unsigned r = v.u + 0x7fffu + ((v.u >> 16) & 1u);   // RNE
  return (short)(r >> 16);
}
__device__ __forceinline__ float bf2f(short x) {
  union { unsigned u; float f; } v;
  v.u = ((unsigned)(unsigned short)x) << 16;
  return v.f;
}

// async global->LDS 16B: dest is wave-uniform base + lane*16 (m104/m108 caveat)
__device__ __forceinline__ void async16(const short* g, short* l) {
  __builtin_amdgcn_global_load_lds(
      (const __attribute__((address_space(1))) void*)(uintptr_t)(const void*)g,
      (__attribute__((address_space(3))) void*)(uintptr_t)(void*)l,
      16, 0, 0);
}

// ---------------- fp32 -> bf16 elementwise (x) ----------------
__global__ void cvt_bf16_kernel(const float* __restrict__ src, short* __restrict__ dst, int n4) {
  int t = blockIdx.x * blockDim.x + threadIdx.x;
  if (t >= n4) return;
  float4 v = ((const float4*)src)[t];
  short4 o;
  o.x = f2bf(v.x); o.y = f2bf(v.y); o.z = f2bf(v.z); o.w = f2bf(v.w);
  *(short4*)(dst + (size_t)t * 4) = o;
}

// ------- fp32 [Kdim][Ndim] -> bf16 transposed [Ndim][Kdim] (weights) -------
__global__ void wtrans_kernel(const float* __restrict__ src, short* __restrict__ dst,
                              int Kdim, int Ndim) {
  __shared__ float tile[32][33];
  int n0 = blockIdx.x * 32, k0 = blockIdx.y * 32;
  for (int r = threadIdx.y; r < 32; r += 8)
    tile[r][threadIdx.x] = src[(size_t)(k0 + r) * Ndim + n0 + threadIdx.x];
  __syncthreads();
  for (int r = threadIdx.y; r < 32; r += 8)
    dst[(size_t)(n0 + r) * Kdim + k0 + threadIdx.x] = f2bf(tile[threadIdx.x][r]);
}

// ---------------- m97-style GEMM: C[M][N] = A[M][K] @ Bt[N][K]^T ----------------
#define BM 128
#define BN 128
#define BK 32

template<int BF16OUT>
__global__ __launch_bounds__(256) void gemm_bt_kernel(const short* __restrict__ A,
    const short* __restrict__ Bt, void* __restrict__ Cv, int M, int N, int K) {
  __shared__ alignas(16) short As[BM * BK];
  __shared__ alignas(16) short Bs[BN * BK];
  const int tid  = threadIdx.x;
  const int wave = tid >> 6;
  const int lane = tid & 63;
  const int quad = lane >> 4;
  const int lr   = lane & 15;
  const int m0 = blockIdx.y * BM;
  const int n0 = blockIdx.x * BN;
  const int wm = (wave >> 1) * 64;
  const int wn = (wave & 1) * 64;

  f32x4 acc[4][4];
#pragma unroll
  for (int i = 0; i < 4; i++)
#pragma unroll
    for (int j = 0; j < 4; j++) acc[i][j] = (f32x4){0.f, 0.f, 0.f, 0.f};

  const int r0 = tid >> 2,          c0 = (tid & 3) * 8;
  const int r1 = (tid + 256) >> 2,  c1 = (tid & 3) * 8;

  for (int kt = 0; kt < K; kt += BK) {
    const short* ga = A  + (size_t)m0 * K + kt;
    const short* gb = Bt + (size_t)n0 * K + kt;
    async16(ga + (size_t)r0 * K + c0, As + wave * 512);
    async16(ga + (size_t)r1 * K + c1, As + 2048 + wave * 512);
    async16(gb + (size_t)r0 * K + c0, Bs + wave * 512);
    async16(gb + (size_t)r1 * K + c1, Bs + 2048 + wave * 512);
    __syncthreads();

    short8 a[4], b[4];
#pragma unroll
    for (int i = 0; i < 4; i++) a[i] = *(const short8*)(As + (wm + i * 16 + lr) * BK + quad * 8);
#pragma unroll
    for (int j = 0; j < 4; j++) b[j] = *(const short8*)(Bs + (wn + j * 16 + lr) * BK + quad * 8);
#pragma unroll
    for (int i = 0; i < 4; i++)
#pragma unroll
      for (int j = 0; j < 4; j++)
        acc[i][j] = __builtin_amdgcn_mfma_f32_16x16x32_bf16(a[i], b[j], acc[i][j], 0, 0, 0);
    __syncthreads();
  }

#pragma unroll
  for (int i = 0; i < 4; i++) {
    const int row = m0 + wm + i * 16 + quad * 4;
#pragma unroll
    for (int j = 0; j < 4; j++) {
      const int col = n0 + wn + j * 16 + lr;
#pragma unroll
      for (int r = 0; r < 4; r++) {
        float v = acc[i][j][r];
        if (BF16OUT) ((short*)Cv)[(size_t)(row + r) * N + col] = f2bf(v);
        else         ((float*)Cv)[(size_t)(row + r) * N + col] = v;
      }
    }
  }
}

// ---------------- RoPE: Q -> Qb [B][NH][S][HD] (scaled); K -> packed frags ----
// Kpack entry: [stream][tile=s/16][c=d/32][lane=quad*16+(s&15)][j=d&7]
//   = K[s][c*32+quad*8+j]  (MFMA A-operand order for the QK^T matmul)
__global__ void rope_kernel(const short* __restrict__ QKVb, short* __restrict__ Qb,
                            short* __restrict__ Kpack) {
  const int head = blockIdx.y;                              // 0..19: 0..15=Q, 16..19=K
  const int t = blockIdx.x * blockDim.x + threadIdx.x;
  const int i = t & 63;
  const int row = t >> 6;                                   // s*B + b
  const int s = row >> 1;
  const int b = row & 1;
  float inv_freq = expf(-(float)i * (1.0f / 64.0f) * 9.210340371976184f); // theta^(-i/64)
  float ang = (float)s * inv_freq;
  float sn, cs;
  sincosf(ang, &sn, &cs);
  if (head < NH) {
    const short* p = QKVb + (size_t)row * NQKV + head * HD;
    float v1 = bf2f(p[i]), v2 = bf2f(p[i + 64]);
    short* q = Qb + ((size_t)(b * NH + head) * S_LEN + s) * HD;
    q[i]      = f2bf((v1 * cs - v2 * sn) * SCALE);
    q[i + 64] = f2bf((v2 * cs + v1 * sn) * SCALE);
  } else {
    const int kv = head - NH;
    const short* p = QKVb + (size_t)row * NQKV + NH * HD + kv * HD;
    float v1 = bf2f(p[i]), v2 = bf2f(p[i + 64]);
    float k1 = v1 * cs - v2 * sn;
    float k2 = v2 * cs + v1 * sn;
    short* kp = Kpack + (size_t)(b * NKV + kv) * S_LEN * HD;
    const int tile = s >> 4, lrr = s & 15;
    const int d1 = i, d2 = i + 64;
    kp[(size_t)((tile * 4 + (d1 >> 5)) * 64 + ((d1 >> 3) & 3) * 16 + lrr) * 8 + (d1 & 7)] = f2bf(k1);
    kp[(size_t)((tile * 4 + (d2 >> 5)) * 64 + ((d2 >> 3) & 3) * 16 + lrr) * 8 + (d2 & 7)] = f2bf(k2);
  }
}

// ---- fused V pack: QKVb V-cols -> Vpack [stream][chunk=s/32][dt=d/16][lane][8] --
// Vpack entry (chunk,dt,lane=quad*16+lr,j) = V[s=chunk*32+quad*8+j][d=dt*16+lr]
// (PV A-operand order; replaces the old vtrans+vpack two-pass)
__global__ void vpack_kernel(const short* __restrict__ QKVb, short* __restrict__ Vpack) {
  __shared__ short tile[32][136];
  const int tid = threadIdx.x;
  const int chunk = blockIdx.x & 63, stream = blockIdx.x >> 6;
  const int b = stream >> 2, kv = stream & 3;
  const int vcol = NH * HD + NKV * HD + kv * HD;
  {
    const int r = tid >> 3, c = (tid & 7) * 16;
    const short* src = QKVb + (size_t)((chunk * 32 + r) * B_SZ + b) * NQKV + vcol + c;
    *(short8*)(&tile[r][c])     = *(const short8*)(src);
    *(short8*)(&tile[r][c + 8]) = *(const short8*)(src + 8);
  }
  __syncthreads();
  const int wave = tid >> 6, lane = tid & 63, quad = lane >> 4, lr = lane & 15;
  short* dst = Vpack + (size_t)stream * HD * S_LEN + chunk * 4096 + lane * 8;
#pragma unroll
  for (int k = 0; k < 2; ++k) {
    const int dt = wave + k * 4;
    short8 v;
#pragma unroll
    for (int j = 0; j < 8; ++j) v[j] = tile[quad * 8 + j][dt * 16 + lr];
    *(short8*)(dst + dt * 512) = v;
  }
}

// ---------------- barrier-free transposed flash attention, 2 heads/wave ---------
// One wave owns one 16-row q-tile for TWO sibling Q-heads of the same KV stream:
// every K/V fragment load is shared by 2 QK / 2 PV MFMAs (halves L1/L2 traffic).
// St = K*Q^T (transposed scores); batched softmax over 64 kv; P round-trips
// through wave-private LDS to become the K=32 PV B-operand.
#define PSP 72   // Ps row pitch in shorts (16B-aligned rows)

__device__ __forceinline__ float softmax_store(const f32x4 sc[4], float& m_i,
    float& l_i, short* __restrict__ Psw, int quad, int lr) {
  float mb = -3.0e38f;
#pragma unroll
  for (int t = 0; t < 4; ++t)
#pragma unroll
    for (int r = 0; r < 4; ++r) mb = fmaxf(mb, sc[t][r]);
  mb = fmaxf(mb, __shfl_xor(mb, 16, 64));
  mb = fmaxf(mb, __shfl_xor(mb, 32, 64));
  const float mnew = fmaxf(m_i, mb);
  const float alpha = __expf(m_i - mnew);
  m_i = mnew;
  float rs = 0.f;
#pragma unroll
  for (int t = 0; t < 4; ++t) {
    short4 pw;
    float p0 = __expf(sc[t][0] - mnew);
    float p1 = __expf(sc[t][1] - mnew);
    float p2 = __expf(sc[t][2] - mnew);
    float p3 = __expf(sc[t][3] - mnew);
    rs += (p0 + p1) + (p2 + p3);
    pw.x = f2bf(p0); pw.y = f2bf(p1); pw.z = f2bf(p2); pw.w = f2bf(p3);
    *(short4*)(Psw + lr * PSP + t * 16 + quad * 4) = pw;   // P^T as [q][kv]
  }
  rs += __shfl_xor(rs, 16, 64);
  rs += __shfl_xor(rs, 32, 64);
  l_i = l_i * alpha + rs;
  return alpha;
}

template<bool MASK>
__device__ __forceinline__ void attn_iter64_2h(
    const short* __restrict__ Kpk, const short* __restrict__ Vpk,
    short* __restrict__ Psw0, short* __restrict__ Psw1,
    const short8 qf0[4], const short8 qf1[4], int kv0, int nt, int qlim,
    int quad, int lr, f32x4 o0[8], f32x4 o1[8],
    float& m_0, float& l_0, float& m_1, float& l_1)
{
  const int lane_off = (quad * 16 + lr) * 8;
  // --- QK^T for both heads, K frags shared (16B/lane coalesced loads) ---
  f32x4 s0[4], s1[4];
#pragma unroll
  for (int t = 0; t < 4; ++t) {
    if (t < nt) {
      const short* kp = Kpk + (size_t)((kv0 >> 4) + t) * 2048 + lane_off;
      f32x4 a0 = (f32x4){0.f, 0.f, 0.f, 0.f};
      f32x4 a1 = (f32x4){0.f, 0.f, 0.f, 0.f};
#pragma unroll
      for (int c = 0; c < 4; ++c) {
        short8 kf = *(const short8*)(kp + c * 512);
        a0 = __builtin_amdgcn_mfma_f32_16x16x32_bf16(kf, qf0[c], a0, 0, 0, 0);
        a1 = __builtin_amdgcn_mfma_f32_16x16x32_bf16(kf, qf1[c], a1, 0, 0, 0);
      }
      s0[t] = a0; s1[t] = a1;
    } else {
      s0[t] = (f32x4){-3.0e38f, -3.0e38f, -3.0e38f, -3.0e38f};
      s1[t] = s0[t];
    }
  }
  // --- causal mask (tail only; both heads share qw) ---
  if (MASK) {
#pragma unroll
    for (int t = 0; t < 4; ++t)
#pragma unroll
      for (int r = 0; r < 4; ++r)
        if (kv0 + t * 16 + quad * 4 + r > qlim) { s0[t][r] = -3.0e38f; s1[t][r] = -3.0e38f; }
  }
  // --- online softmax per head; P -> wave-private LDS ---
  const float al0 = softmax_store(s0, m_0, l_0, Psw0, quad, lr);
  const float al1 = softmax_store(s1, m_1, l_1, Psw1, quad, lr);
#pragma unroll
  for (int n = 0; n < 8; ++n)
#pragma unroll
    for (int r = 0; r < 4; ++r) { o0[n][r] *= al0; o1[n][r] *= al1; }
  // --- PV (K=32), V frags shared across heads ---
  const short* vp = Vpk + (size_t)(kv0 >> 5) * 4096 + lane_off;
  short8 pb0 = *(const short8*)(Psw0 + lr * PSP + quad * 8);
  short8 pb1 = *(const short8*)(Psw1 + lr * PSP + quad * 8);
#pragma unroll
  for (int dt = 0; dt < 8; ++dt) {
    short8 vf = *(const short8*)(vp + dt * 512);
    o0[dt] = __builtin_amdgcn_mfma_f32_16x16x32_bf16(vf, pb0, o0[dt], 0, 0, 0);
    o1[dt] = __builtin_amdgcn_mfma_f32_16x16x32_bf16(vf, pb1, o1[dt], 0, 0, 0);
  }
  if (!MASK || nt > 2) {
    short8 pc0 = *(const short8*)(Psw0 + lr * PSP + 32 + quad * 8);
    short8 pc1 = *(const short8*)(Psw1 + lr * PSP + 32 + quad * 8);
#pragma unroll
    for (int dt = 0; dt < 8; ++dt) {
      short8 vf = *(const short8*)(vp + 4096 + dt * 512);
      o0[dt] = __builtin_amdgcn_mfma_f32_16x16x32_bf16(vf, pc0, o0[dt], 0, 0, 0);
      o1[dt] = __builtin_amdgcn_mfma_f32_16x16x32_bf16(vf, pc1, o1[dt], 0, 0, 0);
    }
  }
}

__global__ __launch_bounds__(256, 2) void attn_kernel(const short* __restrict__ Qb,
    const short* __restrict__ Kpack, const short* __restrict__ Vpack,
    short* __restrict__ Ob) {
  __shared__ alignas(16) short Ps[4][2][16 * PSP];
  const int tid = threadIdx.x, wave = tid >> 6, lane = tid & 63;
  const int quad = lane >> 4, lr = lane & 15;
  const int bid = blockIdx.x;
  const int sid = bid & 7;            // (b,kvh) stream -> XCD L2 affinity
  const int hp  = (bid >> 3) & 1;     // head pair within the stream
  const int qg  = 31 - (bid >> 4);    // heavy q-groups dispatched first
  const int b = sid >> 2, kvh = sid & 3;
  const int h0 = kvh * 4 + hp * 2;
  const int qw = (qg * 4 + wave) * 16;

  const short* Qp0 = Qb    + ((size_t)(b * NH + h0) * S_LEN + qw) * HD;
  const short* Qp1 = Qp0   + (size_t)S_LEN * HD;
  const short* Kpk = Kpack + (size_t)(b * NKV + kvh) * S_LEN * HD;
  const short* Vpk = Vpack + (size_t)(b * NKV + kvh) * HD * S_LEN;
  short* Psw0 = &Ps[wave][0][0];
  short* Psw1 = &Ps[wave][1][0];

  // Q B-fragments (n=q=lr, k=d), loaded once per head
  short8 qf0[4], qf1[4];
#pragma unroll
  for (int c = 0; c < 4; ++c) {
    qf0[c] = *(const short8*)(Qp0 + lr * HD + c * 32 + quad * 8);
    qf1[c] = *(const short8*)(Qp1 + lr * HD + c * 32 + quad * 8);
  }

  f32x4 o0[8], o1[8];
#pragma unroll
  for (int n = 0; n < 8; ++n) { o0[n] = (f32x4){0.f, 0.f, 0.f, 0.f}; o1[n] = o0[n]; }
  float m_0 = -3.0e38f, l_0 = 0.f, m_1 = -3.0e38f, l_1 = 0.f;

  const int full = qw >> 6;
  const int qlim = qw + lr;
  for (int it = 0; it < full; ++it)
    attn_iter64_2h<false>(Kpk, Vpk, Psw0, Psw1, qf0, qf1, it * 64, 4, qlim,
                          quad, lr, o0, o1, m_0, l_0, m_1, l_1);
  attn_iter64_2h<true>(Kpk, Vpk, Psw0, Psw1, qf0, qf1, full * 64,
                       ((qw & 63) >> 4) + 1, qlim, quad, lr, o0, o1,
                       m_0, l_0, m_1, l_1);

  // epilogue: lane holds O^T[d = dt*16+quad*4+r][q = qw+lr] for both heads
  const float invl0 = 1.0f / l_0;
  const float invl1 = 1.0f / l_1;
  short* op0 = Ob + ((size_t)(qw + lr) * B_SZ + b) * D_MODEL + h0 * HD + quad * 4;
#pragma unroll
  for (int dt = 0; dt < 8; ++dt) {
    short4 ov;
    ov.x = f2bf(o0[dt][0] * invl0);
    ov.y = f2bf(o0[dt][1] * invl0);
    ov.z = f2bf(o0[dt][2] * invl0);
    ov.w = f2bf(o0[dt][3] * invl0);
    *(short4*)(op0 + dt * 16) = ov;
    short4 ow;
    ow.x = f2bf(o1[dt][0] * invl1);
    ow.y = f2bf(o1[dt][1] * invl1);
    ow.z = f2bf(o1[dt][2] * invl1);
    ow.w = f2bf(o1[dt][3] * invl1);
    *(short4*)(op0 + HD + dt * 16) = ow;
  }
}

// ---------------- launch ----------------
extern "C" void kernel_launch(void* const* d_in, const int* in_sizes, int n_in,
                              void* d_out, int out_size, void* d_ws, size_t ws_size,
                              hipStream_t stream) {
  (void)in_sizes; (void)n_in; (void)out_size; (void)ws_size;
  const float* x  = (const float*)d_in[0];
  const float* Wq = (const float*)d_in[1];
  const float* Wk = (const float*)d_in[2];
  const float* Wv = (const float*)d_in[3];
  const float* Wo = (const float*)d_in[4];
  float* out = (float*)d_out;
  char* ws = (char*)d_ws;

  // region A [0, 29360128): Wqkv_t(12M)+xb(16M); later Qb(16M)+Kpack(4M)+Vpack(4M)
  short* Wqkv_t = (short*)(ws);                    // [3072][2048]
  short* xb     = (short*)(ws + 12582912);         // [4096][2048]
  short* Qb     = (short*)(ws);                    // [2][16][2048][128]
  short* Kpack  = (short*)(ws + 16777216);         // packed K frags, 4MB
  short* Vpack  = (short*)(ws + 25165824);         // packed V^T frags, 4MB
  // region B [29360128, 54525952): QKVb(24M); later Ob(16M)
  short* QKVb   = (short*)(ws + 29360128);         // [4096][3072]
  short* Ob     = (short*)(ws + 29360128);         // [4096][2048]
  // region C [54525952, 62914560): Wo_t(8M)
  short* Wo_t   = (short*)(ws + 54525952);         // [2048][2048]

  dim3 tblk(32, 8);

  // 1. x -> bf16
  cvt_bf16_kernel<<<(ROWS * D_MODEL / 4 + 255) / 256, 256, 0, stream>>>(x, xb, ROWS * D_MODEL / 4);
  // 2. weight transposes to B^T layout (bf16)
  wtrans_kernel<<<dim3(64, 64), tblk, 0, stream>>>(Wq, Wqkv_t,               2048, 2048);
  wtrans_kernel<<<dim3(16, 64), tblk, 0, stream>>>(Wk, Wqkv_t + 2048 * 2048, 2048,  512);
  wtrans_kernel<<<dim3(16, 64), tblk, 0, stream>>>(Wv, Wqkv_t + 2560 * 2048, 2048,  512);
  wtrans_kernel<<<dim3(64, 64), tblk, 0, stream>>>(Wo, Wo_t,                 2048, 2048);
  // 3. QKV projection (bf16 out)
  gemm_bt_kernel<1><<<dim3(NQKV / BN, ROWS / BM), 256, 0, stream>>>(xb, Wqkv_t, QKVb, ROWS, NQKV, D_MODEL);
  // 4. RoPE: Q -> Qb, K -> packed frags
  rope_kernel<<<dim3(1024, NH + NKV), 256, 0, stream>>>(QKVb, Qb, Kpack);
  // 5. fused V pack (QKVb -> PV A-operand layout)
  vpack_kernel<<<dim3(512), 256, 0, stream>>>(QKVb, Vpack);
  // 6. causal flash attention (barrier-free, 2 heads/wave share K/V frags)
  attn_kernel<<<dim3(512), 256, 0, stream>>>(Qb, Kpack, Vpack, Ob);
  // 7. output projection (fp32 out)
  gemm_bt_kernel<0><<<dim3(D_MODEL / BN, ROWS / BM), 256, 0, stream>>>(Ob, Wo_t, out, ROWS, D_MODEL, D_MODEL);
}

// Round 5
// 342.903 us; speedup vs baseline: 1.2639x; 1.2639x over previous
//
#include <hip/hip_runtime.h>
#include <hip/hip_bf16.h>
#include <cstdint>
#include <math.h>

// Problem constants
#define S_LEN   2048
#define B_SZ    2
#define D_MODEL 2048
#define NH      16
#define NKV     4
#define HD      128
#define ROWS    (S_LEN * B_SZ)          // 4096
#define NQKV    3072                    // NH*HD + 2*NKV*HD
#define SCALE   0.08838834764831845f    // 1/sqrt(HD)

typedef __attribute__((ext_vector_type(8))) short short8;   // 8 bf16 = 4 VGPRs
typedef __attribute__((ext_vector_type(4))) float f32x4;    // MFMA acc

__device__ __forceinline__ short f2bf(float f) {
  union { float f; unsigned u; } v; v.f = f;
  unsigned r = v.u + 0x7fffu + ((v.u >> 16) & 1u);   // RNE
  return (short)(r >> 16);
}
__device__ __forceinline__ float bf2f(short x) {
  union { unsigned u; float f; } v;
  v.u = ((unsigned)(unsigned short)x) << 16;
  return v.f;
}

// async global->LDS 16B: dest is wave-uniform base + lane*16 (m104/m108 caveat)
__device__ __forceinline__ void async16(const short* g, short* l) {
  __builtin_amdgcn_global_load_lds(
      (const __attribute__((address_space(1))) void*)(uintptr_t)(const void*)g,
      (__attribute__((address_space(3))) void*)(uintptr_t)(void*)l,
      16, 0, 0);
}

// ---------------- fp32 -> bf16 elementwise (x) ----------------
__global__ void cvt_bf16_kernel(const float* __restrict__ src, short* __restrict__ dst, int n4) {
  int t = blockIdx.x * blockDim.x + threadIdx.x;
  if (t >= n4) return;
  float4 v = ((const float4*)src)[t];
  short4 o;
  o.x = f2bf(v.x); o.y = f2bf(v.y); o.z = f2bf(v.z); o.w = f2bf(v.w);
  *(short4*)(dst + (size_t)t * 4) = o;
}

// ------- fp32 [Kdim][Ndim] -> bf16 transposed [Ndim][Kdim] (weights) -------
__global__ void wtrans_kernel(const float* __restrict__ src, short* __restrict__ dst,
                              int Kdim, int Ndim) {
  __shared__ float tile[32][33];
  int n0 = blockIdx.x * 32, k0 = blockIdx.y * 32;
  for (int r = threadIdx.y; r < 32; r += 8)
    tile[r][threadIdx.x] = src[(size_t)(k0 + r) * Ndim + n0 + threadIdx.x];
  __syncthreads();
  for (int r = threadIdx.y; r < 32; r += 8)
    dst[(size_t)(n0 + r) * Kdim + k0 + threadIdx.x] = f2bf(tile[threadIdx.x][r]);
}

// ---------------- m97-style GEMM: C[M][N] = A[M][K] @ Bt[N][K]^T ----------------
#define BM 128
#define BN 128
#define BK 32

template<int BF16OUT>
__global__ __launch_bounds__(256) void gemm_bt_kernel(const short* __restrict__ A,
    const short* __restrict__ Bt, void* __restrict__ Cv, int M, int N, int K) {
  __shared__ alignas(16) short As[BM * BK];
  __shared__ alignas(16) short Bs[BN * BK];
  const int tid  = threadIdx.x;
  const int wave = tid >> 6;
  const int lane = tid & 63;
  const int quad = lane >> 4;
  const int lr   = lane & 15;
  const int m0 = blockIdx.y * BM;
  const int n0 = blockIdx.x * BN;
  const int wm = (wave >> 1) * 64;
  const int wn = (wave & 1) * 64;

  f32x4 acc[4][4];
#pragma unroll
  for (int i = 0; i < 4; i++)
#pragma unroll
    for (int j = 0; j < 4; j++) acc[i][j] = (f32x4){0.f, 0.f, 0.f, 0.f};

  const int r0 = tid >> 2,          c0 = (tid & 3) * 8;
  const int r1 = (tid + 256) >> 2,  c1 = (tid & 3) * 8;

  for (int kt = 0; kt < K; kt += BK) {
    const short* ga = A  + (size_t)m0 * K + kt;
    const short* gb = Bt + (size_t)n0 * K + kt;
    async16(ga + (size_t)r0 * K + c0, As + wave * 512);
    async16(ga + (size_t)r1 * K + c1, As + 2048 + wave * 512);
    async16(gb + (size_t)r0 * K + c0, Bs + wave * 512);
    async16(gb + (size_t)r1 * K + c1, Bs + 2048 + wave * 512);
    __syncthreads();

    short8 a[4], b[4];
#pragma unroll
    for (int i = 0; i < 4; i++) a[i] = *(const short8*)(As + (wm + i * 16 + lr) * BK + quad * 8);
#pragma unroll
    for (int j = 0; j < 4; j++) b[j] = *(const short8*)(Bs + (wn + j * 16 + lr) * BK + quad * 8);
#pragma unroll
    for (int i = 0; i < 4; i++)
#pragma unroll
      for (int j = 0; j < 4; j++)
        acc[i][j] = __builtin_amdgcn_mfma_f32_16x16x32_bf16(a[i], b[j], acc[i][j], 0, 0, 0);
    __syncthreads();
  }

#pragma unroll
  for (int i = 0; i < 4; i++) {
    const int row = m0 + wm + i * 16 + quad * 4;
#pragma unroll
    for (int j = 0; j < 4; j++) {
      const int col = n0 + wn + j * 16 + lr;
#pragma unroll
      for (int r = 0; r < 4; r++) {
        float v = acc[i][j][r];
        if (BF16OUT) ((short*)Cv)[(size_t)(row + r) * N + col] = f2bf(v);
        else         ((float*)Cv)[(size_t)(row + r) * N + col] = v;
      }
    }
  }
}

// ---------------- RoPE: Q -> Qb [B][NH][S][HD] (scaled); K -> packed frags ----
// Kpack entry: [stream][tile=s/16][c=d/32][lane=quad*16+(s&15)][j=d&7]
//   = K[s][c*32+quad*8+j]  (MFMA A-operand order for the QK^T matmul)
__global__ void rope_kernel(const short* __restrict__ QKVb, short* __restrict__ Qb,
                            short* __restrict__ Kpack) {
  const int head = blockIdx.y;                              // 0..19: 0..15=Q, 16..19=K
  const int t = blockIdx.x * blockDim.x + threadIdx.x;
  const int i = t & 63;
  const int row = t >> 6;                                   // s*B + b
  const int s = row >> 1;
  const int b = row & 1;
  float inv_freq = expf(-(float)i * (1.0f / 64.0f) * 9.210340371976184f); // theta^(-i/64)
  float ang = (float)s * inv_freq;
  float sn, cs;
  sincosf(ang, &sn, &cs);
  if (head < NH) {
    const short* p = QKVb + (size_t)row * NQKV + head * HD;
    float v1 = bf2f(p[i]), v2 = bf2f(p[i + 64]);
    short* q = Qb + ((size_t)(b * NH + head) * S_LEN + s) * HD;
    q[i]      = f2bf((v1 * cs - v2 * sn) * SCALE);
    q[i + 64] = f2bf((v2 * cs + v1 * sn) * SCALE);
  } else {
    const int kv = head - NH;
    const short* p = QKVb + (size_t)row * NQKV + NH * HD + kv * HD;
    float v1 = bf2f(p[i]), v2 = bf2f(p[i + 64]);
    float k1 = v1 * cs - v2 * sn;
    float k2 = v2 * cs + v1 * sn;
    short* kp = Kpack + (size_t)(b * NKV + kv) * S_LEN * HD;
    const int tile = s >> 4, lrr = s & 15;
    const int d1 = i, d2 = i + 64;
    kp[(size_t)((tile * 4 + (d1 >> 5)) * 64 + ((d1 >> 3) & 3) * 16 + lrr) * 8 + (d1 & 7)] = f2bf(k1);
    kp[(size_t)((tile * 4 + (d2 >> 5)) * 64 + ((d2 >> 3) & 3) * 16 + lrr) * 8 + (d2 & 7)] = f2bf(k2);
  }
}

// ---- fused V pack: QKVb V-cols -> Vpack [stream][chunk=s/32][dt=d/16][lane][8] --
// Vpack entry (chunk,dt,lane=quad*16+lr,j) = V[s=chunk*32+quad*8+j][d=dt*16+lr]
// (PV A-operand order; single pass, validated in R4)
__global__ void vpack_kernel(const short* __restrict__ QKVb, short* __restrict__ Vpack) {
  __shared__ short tile[32][136];
  const int tid = threadIdx.x;
  const int chunk = blockIdx.x & 63, stream = blockIdx.x >> 6;
  const int b = stream >> 2, kv = stream & 3;
  const int vcol = NH * HD + NKV * HD + kv * HD;
  {
    const int r = tid >> 3, c = (tid & 7) * 16;
    const short* src = QKVb + (size_t)((chunk * 32 + r) * B_SZ + b) * NQKV + vcol + c;
    *(short8*)(&tile[r][c])     = *(const short8*)(src);
    *(short8*)(&tile[r][c + 8]) = *(const short8*)(src + 8);
  }
  __syncthreads();
  const int wave = tid >> 6, lane = tid & 63, quad = lane >> 4, lr = lane & 15;
  short* dst = Vpack + (size_t)stream * HD * S_LEN + chunk * 4096 + lane * 8;
#pragma unroll
  for (int k = 0; k < 2; ++k) {
    const int dt = wave + k * 4;
    short8 v;
#pragma unroll
    for (int j = 0; j < 8; ++j) v[j] = tile[quad * 8 + j][dt * 16 + lr];
    *(short8*)(dst + dt * 512) = v;
  }
}

// ---------------- barrier-free transposed flash attention, 64-kv iters ----------
// (R3 structure: one wave per 16-row q-tile; this was the 85 µs configuration.
//  R4's 2-heads/wave halved TLP and doubled time — waves are the latency-hiding
//  resource here; do not trade them for reuse.)
// St = K*Q^T via packed K frags (coalesced 1KB loads). Batched softmax over
// 64 kv (2+2 shuffles). P round-trips through wave-private LDS (no barrier)
// to become the B-operand of a K=32 PV MFMA against packed V^T frags.
#define PSP 72   // Ps row pitch in shorts (16B-aligned rows)

template<bool MASK>
__device__ __forceinline__ void attn_iter64(
    const short* __restrict__ Kpk, const short* __restrict__ Vpk,
    short* __restrict__ Psw, const short8 qf[4], int kv0, int nt, int qlim,
    int quad, int lr, f32x4 o[8], float& m_i, float& l_i)
{
  const int lane_off = (quad * 16 + lr) * 8;
  // --- K fragment loads (16B/lane, coalesced) ---
  short8 kf[4][4];
#pragma unroll
  for (int t = 0; t < 4; ++t)
    if (t < nt) {
      const short* kp = Kpk + (size_t)((kv0 >> 4) + t) * 2048 + lane_off;
#pragma unroll
      for (int c = 0; c < 4; ++c)
        kf[t][c] = *(const short8*)(kp + c * 512);
    }
  // --- QK^T (transposed scores: St[kv=quad*4+r][q=lr]) ---
  f32x4 sc[4];
#pragma unroll
  for (int t = 0; t < 4; ++t) {
    if (t < nt) {
      f32x4 s = (f32x4){0.f, 0.f, 0.f, 0.f};
#pragma unroll
      for (int c = 0; c < 4; ++c)
        s = __builtin_amdgcn_mfma_f32_16x16x32_bf16(kf[t][c], qf[c], s, 0, 0, 0);
      sc[t] = s;
    } else {
      sc[t] = (f32x4){-3.0e38f, -3.0e38f, -3.0e38f, -3.0e38f};
    }
  }
  // --- V fragment loads (issued before softmax VALU for overlap) ---
  const bool c1v = !MASK || (nt > 2);
  short8 vf0[8], vf1[8];
  const short* vp = Vpk + (size_t)(kv0 >> 5) * 4096 + lane_off;
#pragma unroll
  for (int dt = 0; dt < 8; ++dt) vf0[dt] = *(const short8*)(vp + dt * 512);
  if (c1v) {
#pragma unroll
    for (int dt = 0; dt < 8; ++dt) vf1[dt] = *(const short8*)(vp + 4096 + dt * 512);
  }
  // --- causal mask (tail only) ---
  if (MASK) {
#pragma unroll
    for (int t = 0; t < 4; ++t)
#pragma unroll
      for (int r = 0; r < 4; ++r)
        if (kv0 + t * 16 + quad * 4 + r > qlim) sc[t][r] = -3.0e38f;
  }
  // --- batched online softmax (per-lane column stats, q = lr) ---
  float mb = -3.0e38f;
#pragma unroll
  for (int t = 0; t < 4; ++t)
#pragma unroll
    for (int r = 0; r < 4; ++r) mb = fmaxf(mb, sc[t][r]);
  mb = fmaxf(mb, __shfl_xor(mb, 16, 64));
  mb = fmaxf(mb, __shfl_xor(mb, 32, 64));
  const float mnew = fmaxf(m_i, mb);
  const float alpha = __expf(m_i - mnew);
  m_i = mnew;
  float rs = 0.f;
#pragma unroll
  for (int t = 0; t < 4; ++t) {
    float p0 = __expf(sc[t][0] - mnew);
    float p1 = __expf(sc[t][1] - mnew);
    float p2 = __expf(sc[t][2] - mnew);
    float p3 = __expf(sc[t][3] - mnew);
    rs += (p0 + p1) + (p2 + p3);
    // packed bf16 conversion (v_cvt_pk_bf16_f32): 2 insts instead of ~12
    __hip_bfloat162 pk01 = __float22bfloat162_rn(make_float2(p0, p1));
    __hip_bfloat162 pk23 = __float22bfloat162_rn(make_float2(p2, p3));
    __hip_bfloat162* pd = (__hip_bfloat162*)(Psw + lr * PSP + t * 16 + quad * 4);
    pd[0] = pk01;
    pd[1] = pk23;
  }
  rs += __shfl_xor(rs, 16, 64);
  rs += __shfl_xor(rs, 32, 64);
  l_i = l_i * alpha + rs;
#pragma unroll
  for (int n = 0; n < 8; ++n)
#pragma unroll
    for (int r = 0; r < 4; ++r) o[n][r] *= alpha;
  // --- P B-frags (K=32) from wave-private LDS; PV ---
  short8 pb0 = *(const short8*)(Psw + lr * PSP + quad * 8);
#pragma unroll
  for (int dt = 0; dt < 8; ++dt)
    o[dt] = __builtin_amdgcn_mfma_f32_16x16x32_bf16(vf0[dt], pb0, o[dt], 0, 0, 0);
  if (c1v) {
    short8 pb1 = *(const short8*)(Psw + lr * PSP + 32 + quad * 8);
#pragma unroll
    for (int dt = 0; dt < 8; ++dt)
      o[dt] = __builtin_amdgcn_mfma_f32_16x16x32_bf16(vf1[dt], pb1, o[dt], 0, 0, 0);
  }
}

__global__ __launch_bounds__(256) void attn_kernel(const short* __restrict__ Qb,
    const short* __restrict__ Kpack, const short* __restrict__ Vpack,
    short* __restrict__ Ob) {
  __shared__ alignas(16) short Ps[4][16 * PSP];
  const int tid = threadIdx.x, wave = tid >> 6, lane = tid & 63;
  const int quad = lane >> 4, lr = lane & 15;
  const int bid = blockIdx.x;
  const int sid  = bid & 7;           // (b,kvh) stream -> XCD L2 affinity
  const int hsub = (bid >> 3) & 3;
  const int qg   = 31 - (bid >> 5);   // heavy q-groups dispatched first
  const int b = sid >> 2, kvh = sid & 3;
  const int h = kvh * 4 + hsub;
  const int qw = (qg * 4 + wave) * 16;

  const short* Qp  = Qb    + ((size_t)(b * NH + h) * S_LEN + qw) * HD;
  const short* Kpk = Kpack + (size_t)(b * NKV + kvh) * S_LEN * HD;
  const short* Vpk = Vpack + (size_t)(b * NKV + kvh) * HD * S_LEN;
  short* Psw = &Ps[wave][0];

  // Q B-fragments (n=q=lr, k=d), loaded once
  short8 qf[4];
#pragma unroll
  for (int c = 0; c < 4; ++c)
    qf[c] = *(const short8*)(Qp + lr * HD + c * 32 + quad * 8);

  f32x4 o[8];
#pragma unroll
  for (int n = 0; n < 8; ++n) o[n] = (f32x4){0.f, 0.f, 0.f, 0.f};
  float m_i = -3.0e38f, l_i = 0.f;

  const int full = qw >> 6;
  const int qlim = qw + lr;
  for (int it = 0; it < full; ++it)
    attn_iter64<false>(Kpk, Vpk, Psw, qf, it * 64, 4, qlim, quad, lr, o, m_i, l_i);
  attn_iter64<true>(Kpk, Vpk, Psw, qf, full * 64, ((qw & 63) >> 4) + 1, qlim,
                    quad, lr, o, m_i, l_i);

  // epilogue: lane holds O^T[d = dt*16+quad*4+r][q = qw+lr]
  const float invl = 1.0f / l_i;
  short* op = Ob + ((size_t)(qw + lr) * B_SZ + b) * D_MODEL + h * HD + quad * 4;
#pragma unroll
  for (int dt = 0; dt < 8; ++dt) {
    short4 ov;
    ov.x = f2bf(o[dt][0] * invl);
    ov.y = f2bf(o[dt][1] * invl);
    ov.z = f2bf(o[dt][2] * invl);
    ov.w = f2bf(o[dt][3] * invl);
    *(short4*)(op + dt * 16) = ov;
  }
}

// ---------------- launch ----------------
extern "C" void kernel_launch(void* const* d_in, const int* in_sizes, int n_in,
                              void* d_out, int out_size, void* d_ws, size_t ws_size,
                              hipStream_t stream) {
  (void)in_sizes; (void)n_in; (void)out_size; (void)ws_size;
  const float* x  = (const float*)d_in[0];
  const float* Wq = (const float*)d_in[1];
  const float* Wk = (const float*)d_in[2];
  const float* Wv = (const float*)d_in[3];
  const float* Wo = (const float*)d_in[4];
  float* out = (float*)d_out;
  char* ws = (char*)d_ws;

  // region A [0, 29360128): Wqkv_t(12M)+xb(16M); later Qb(16M)+Kpack(4M)+Vpack(4M)
  short* Wqkv_t = (short*)(ws);                    // [3072][2048]
  short* xb     = (short*)(ws + 12582912);         // [4096][2048]
  short* Qb     = (short*)(ws);                    // [2][16][2048][128]
  short* Kpack  = (short*)(ws + 16777216);         // packed K frags, 4MB
  short* Vpack  = (short*)(ws + 25165824);         // packed V^T frags, 4MB
  // region B [29360128, 54525952): QKVb(24M); later Ob(16M)
  short* QKVb   = (short*)(ws + 29360128);         // [4096][3072]
  short* Ob     = (short*)(ws + 29360128);         // [4096][2048]
  // region C [54525952, 62914560): Wo_t(8M)
  short* Wo_t   = (short*)(ws + 54525952);         // [2048][2048]

  dim3 tblk(32, 8);

  // 1. x -> bf16
  cvt_bf16_kernel<<<(ROWS * D_MODEL / 4 + 255) / 256, 256, 0, stream>>>(x, xb, ROWS * D_MODEL / 4);
  // 2. weight transposes to B^T layout (bf16)
  wtrans_kernel<<<dim3(64, 64), tblk, 0, stream>>>(Wq, Wqkv_t,               2048, 2048);
  wtrans_kernel<<<dim3(16, 64), tblk, 0, stream>>>(Wk, Wqkv_t + 2048 * 2048, 2048,  512);
  wtrans_kernel<<<dim3(16, 64), tblk, 0, stream>>>(Wv, Wqkv_t + 2560 * 2048, 2048,  512);
  wtrans_kernel<<<dim3(64, 64), tblk, 0, stream>>>(Wo, Wo_t,                 2048, 2048);
  // 3. QKV projection (bf16 out)
  gemm_bt_kernel<1><<<dim3(NQKV / BN, ROWS / BM), 256, 0, stream>>>(xb, Wqkv_t, QKVb, ROWS, NQKV, D_MODEL);
  // 4. RoPE: Q -> Qb, K -> packed frags
  rope_kernel<<<dim3(1024, NH + NKV), 256, 0, stream>>>(QKVb, Qb, Kpack);
  // 5. fused V pack (QKVb -> PV A-operand layout)
  vpack_kernel<<<dim3(512), 256, 0, stream>>>(QKVb, Vpack);
  // 6. causal flash attention (barrier-free, one wave per 16-row q-tile)
  attn_kernel<<<dim3(1024), 256, 0, stream>>>(Qb, Kpack, Vpack, Ob);
  // 7. output projection (fp32 out)
  gemm_bt_kernel<0><<<dim3(D_MODEL / BN, ROWS / BM), 256, 0, stream>>>(Ob, Wo_t, out, ROWS, D_MODEL, D_MODEL);
}

// Round 6
// 326.093 us; speedup vs baseline: 1.3290x; 1.0515x over previous
//
#include <hip/hip_runtime.h>
#include <hip/hip_bf16.h>
#include <cstdint>
#include <math.h>

// Problem constants
#define S_LEN   2048
#define B_SZ    2
#define D_MODEL 2048
#define NH      16
#define NKV     4
#define HD      128
#define ROWS    (S_LEN * B_SZ)          // 4096
#define NQKV    3072                    // NH*HD + 2*NKV*HD
#define SCALE   0.08838834764831845f    // 1/sqrt(HD)

typedef __attribute__((ext_vector_type(8))) short short8;   // 8 bf16 = 4 VGPRs
typedef __attribute__((ext_vector_type(4))) float f32x4;    // MFMA acc

__device__ __forceinline__ short f2bf(float f) {
  union { float f; unsigned u; } v; v.f = f;
  unsigned r = v.u + 0x7fffu + ((v.u >> 16) & 1u);   // RNE
  return (short)(r >> 16);
}
__device__ __forceinline__ float bf2f(short x) {
  union { unsigned u; float f; } v;
  v.u = ((unsigned)(unsigned short)x) << 16;
  return v.f;
}

// async global->LDS 16B: dest is wave-uniform base + lane*16 (m104/m108 caveat)
__device__ __forceinline__ void async16(const short* g, short* l) {
  __builtin_amdgcn_global_load_lds(
      (const __attribute__((address_space(1))) void*)(uintptr_t)(const void*)g,
      (__attribute__((address_space(3))) void*)(uintptr_t)(void*)l,
      16, 0, 0);
}

// ---------------- fp32 -> bf16 elementwise (x) ----------------
__global__ void cvt_bf16_kernel(const float* __restrict__ src, short* __restrict__ dst, int n4) {
  int t = blockIdx.x * blockDim.x + threadIdx.x;
  if (t >= n4) return;
  float4 v = ((const float4*)src)[t];
  short4 o;
  o.x = f2bf(v.x); o.y = f2bf(v.y); o.z = f2bf(v.z); o.w = f2bf(v.w);
  *(short4*)(dst + (size_t)t * 4) = o;
}

// ------- fp32 [2048][N] -> bf16 transposed; Wq/Wk/Wv merged in one launch -------
__global__ void wtrans_qkv_kernel(const float* __restrict__ Wq,
                                  const float* __restrict__ Wk,
                                  const float* __restrict__ Wv,
                                  short* __restrict__ dst) {
  __shared__ float tile[32][33];
  const int bx = blockIdx.x;
  const float* src;
  int Ndim, n0, drow;
  if (bx < 64)      { src = Wq; Ndim = 2048; n0 = bx * 32;        drow = n0; }
  else if (bx < 80) { src = Wk; Ndim = 512;  n0 = (bx - 64) * 32; drow = 2048 + n0; }
  else              { src = Wv; Ndim = 512;  n0 = (bx - 80) * 32; drow = 2560 + n0; }
  const int k0 = blockIdx.y * 32;
  for (int r = threadIdx.y; r < 32; r += 8)
    tile[r][threadIdx.x] = src[(size_t)(k0 + r) * Ndim + n0 + threadIdx.x];
  __syncthreads();
  for (int r = threadIdx.y; r < 32; r += 8)
    dst[(size_t)(drow + r) * 2048 + k0 + threadIdx.x] = f2bf(tile[threadIdx.x][r]);
}

__global__ void wtrans_kernel(const float* __restrict__ src, short* __restrict__ dst,
                              int Kdim, int Ndim) {
  __shared__ float tile[32][33];
  int n0 = blockIdx.x * 32, k0 = blockIdx.y * 32;
  for (int r = threadIdx.y; r < 32; r += 8)
    tile[r][threadIdx.x] = src[(size_t)(k0 + r) * Ndim + n0 + threadIdx.x];
  __syncthreads();
  for (int r = threadIdx.y; r < 32; r += 8)
    dst[(size_t)(n0 + r) * Kdim + k0 + threadIdx.x] = f2bf(tile[threadIdx.x][r]);
}

// ---------------- m97-style GEMM: C[M][N] = A[M][K] @ Bt[N][K]^T ----------------
#define BM 128
#define BN 128
#define BK 32

template<int BF16OUT>
__global__ __launch_bounds__(256) void gemm_bt_kernel(const short* __restrict__ A,
    const short* __restrict__ Bt, void* __restrict__ Cv, int M, int N, int K) {
  __shared__ alignas(16) short As[BM * BK];
  __shared__ alignas(16) short Bs[BN * BK];
  const int tid  = threadIdx.x;
  const int wave = tid >> 6;
  const int lane = tid & 63;
  const int quad = lane >> 4;
  const int lr   = lane & 15;
  const int m0 = blockIdx.y * BM;
  const int n0 = blockIdx.x * BN;
  const int wm = (wave >> 1) * 64;
  const int wn = (wave & 1) * 64;

  f32x4 acc[4][4];
#pragma unroll
  for (int i = 0; i < 4; i++)
#pragma unroll
    for (int j = 0; j < 4; j++) acc[i][j] = (f32x4){0.f, 0.f, 0.f, 0.f};

  const int r0 = tid >> 2,          c0 = (tid & 3) * 8;
  const int r1 = (tid + 256) >> 2,  c1 = (tid & 3) * 8;

  for (int kt = 0; kt < K; kt += BK) {
    const short* ga = A  + (size_t)m0 * K + kt;
    const short* gb = Bt + (size_t)n0 * K + kt;
    async16(ga + (size_t)r0 * K + c0, As + wave * 512);
    async16(ga + (size_t)r1 * K + c1, As + 2048 + wave * 512);
    async16(gb + (size_t)r0 * K + c0, Bs + wave * 512);
    async16(gb + (size_t)r1 * K + c1, Bs + 2048 + wave * 512);
    __syncthreads();

    short8 a[4], b[4];
#pragma unroll
    for (int i = 0; i < 4; i++) a[i] = *(const short8*)(As + (wm + i * 16 + lr) * BK + quad * 8);
#pragma unroll
    for (int j = 0; j < 4; j++) b[j] = *(const short8*)(Bs + (wn + j * 16 + lr) * BK + quad * 8);
#pragma unroll
    for (int i = 0; i < 4; i++)
#pragma unroll
      for (int j = 0; j < 4; j++)
        acc[i][j] = __builtin_amdgcn_mfma_f32_16x16x32_bf16(a[i], b[j], acc[i][j], 0, 0, 0);
    __syncthreads();
  }

#pragma unroll
  for (int i = 0; i < 4; i++) {
    const int row = m0 + wm + i * 16 + quad * 4;
#pragma unroll
    for (int j = 0; j < 4; j++) {
      const int col = n0 + wn + j * 16 + lr;
#pragma unroll
      for (int r = 0; r < 4; r++) {
        float v = acc[i][j][r];
        if (BF16OUT) ((short*)Cv)[(size_t)(row + r) * N + col] = f2bf(v);
        else         ((float*)Cv)[(size_t)(row + r) * N + col] = v;
      }
    }
  }
}

// ---------------- RoPE: Q -> Qb [B][NH][S][HD] (scaled); K -> packed frags ----
// Kpack entry: [stream][tile=s/16][c=d/32][lane=quad*16+(s&15)][j=d&7]
//   = K[s][c*32+quad*8+j]  (MFMA A-operand order for the QK^T matmul)
__global__ void rope_kernel(const short* __restrict__ QKVb, short* __restrict__ Qb,
                            short* __restrict__ Kpack) {
  const int head = blockIdx.y;                              // 0..19: 0..15=Q, 16..19=K
  const int t = blockIdx.x * blockDim.x + threadIdx.x;
  const int i = t & 63;
  const int row = t >> 6;                                   // s*B + b
  const int s = row >> 1;
  const int b = row & 1;
  float inv_freq = __expf(-(float)i * (1.0f / 64.0f) * 9.210340371976184f); // theta^(-i/64)
  float ang = (float)s * inv_freq;
  float sn, cs;
  __sincosf(ang, &sn, &cs);
  if (head < NH) {
    const short* p = QKVb + (size_t)row * NQKV + head * HD;
    float v1 = bf2f(p[i]), v2 = bf2f(p[i + 64]);
    short* q = Qb + ((size_t)(b * NH + head) * S_LEN + s) * HD;
    q[i]      = f2bf((v1 * cs - v2 * sn) * SCALE);
    q[i + 64] = f2bf((v2 * cs + v1 * sn) * SCALE);
  } else {
    const int kv = head - NH;
    const short* p = QKVb + (size_t)row * NQKV + NH * HD + kv * HD;
    float v1 = bf2f(p[i]), v2 = bf2f(p[i + 64]);
    float k1 = v1 * cs - v2 * sn;
    float k2 = v2 * cs + v1 * sn;
    short* kp = Kpack + (size_t)(b * NKV + kv) * S_LEN * HD;
    const int tile = s >> 4, lrr = s & 15;
    const int d1 = i, d2 = i + 64;
    kp[(size_t)((tile * 4 + (d1 >> 5)) * 64 + ((d1 >> 3) & 3) * 16 + lrr) * 8 + (d1 & 7)] = f2bf(k1);
    kp[(size_t)((tile * 4 + (d2 >> 5)) * 64 + ((d2 >> 3) & 3) * 16 + lrr) * 8 + (d2 & 7)] = f2bf(k2);
  }
}

// ---- fused V pack: QKVb V-cols -> Vpack [stream][chunk=s/32][dt=d/16][lane][8] --
// Vpack entry (chunk,dt,lane=quad*16+lr,j) = V[s=chunk*32+quad*8+j][d=dt*16+lr]
__global__ void vpack_kernel(const short* __restrict__ QKVb, short* __restrict__ Vpack) {
  __shared__ short tile[32][136];
  const int tid = threadIdx.x;
  const int chunk = blockIdx.x & 63, stream = blockIdx.x >> 6;
  const int b = stream >> 2, kv = stream & 3;
  const int vcol = NH * HD + NKV * HD + kv * HD;
  {
    const int r = tid >> 3, c = (tid & 7) * 16;
    const short* src = QKVb + (size_t)((chunk * 32 + r) * B_SZ + b) * NQKV + vcol + c;
    *(short8*)(&tile[r][c])     = *(const short8*)(src);
    *(short8*)(&tile[r][c + 8]) = *(const short8*)(src + 8);
  }
  __syncthreads();
  const int wave = tid >> 6, lane = tid & 63, quad = lane >> 4, lr = lane & 15;
  short* dst = Vpack + (size_t)stream * HD * S_LEN + chunk * 4096 + lane * 8;
#pragma unroll
  for (int k = 0; k < 2; ++k) {
    const int dt = wave + k * 4;
    short8 v;
#pragma unroll
    for (int j = 0; j < 8; ++j) v[j] = tile[quad * 8 + j][dt * 16 + lr];
    *(short8*)(dst + dt * 512) = v;
  }
}

// ------- transposed flash attention, block-shared LDS K/V staging -------
// 4 waves/block share one (b,kvh) stream and stage each 64-kv K/V tile (32KB)
// into LDS via async16 (layouts are fragment-linear, so staging is a straight
// contiguous copy; frag reads are ds_read_b128 with free 2-way bank aliasing).
// VMEM traffic /4 vs R5 (the L2-feed was the binder). 2 barriers/iter,
// uniform per-block loop count; tail masks per wave (masked p underflow to 0).
// Softmax/P round-trip (wave-private LDS) unchanged from R5.
#define PSP 72   // Ps row pitch in shorts (16B-aligned rows)

template<bool MASK>
__device__ __forceinline__ void attn_iter64(
    const short* __restrict__ Ks, const short* __restrict__ Vs,
    short* __restrict__ Psw, const short8 qf[4], int kv0, int nt, int qlim,
    int quad, int lr, int lane, f32x4 o[8], float& m_i, float& l_i)
{
  const int lane_off = lane * 8;
  // --- QK^T (transposed scores: St[kv=quad*4+r][q=lr]), K frags from LDS ---
  f32x4 sc[4];
#pragma unroll
  for (int t = 0; t < 4; ++t) {
    if (t < nt) {
      const short* kp = Ks + t * 2048 + lane_off;
      f32x4 s = (f32x4){0.f, 0.f, 0.f, 0.f};
#pragma unroll
      for (int c = 0; c < 4; ++c) {
        short8 kf = *(const short8*)(kp + c * 512);
        s = __builtin_amdgcn_mfma_f32_16x16x32_bf16(kf, qf[c], s, 0, 0, 0);
      }
      sc[t] = s;
    } else {
      sc[t] = (f32x4){-3.0e38f, -3.0e38f, -3.0e38f, -3.0e38f};
    }
  }
  // --- causal mask (tail only) ---
  if (MASK) {
#pragma unroll
    for (int t = 0; t < 4; ++t)
#pragma unroll
      for (int r = 0; r < 4; ++r)
        if (kv0 + t * 16 + quad * 4 + r > qlim) sc[t][r] = -3.0e38f;
  }
  // --- batched online softmax (per-lane column stats, q = lr) ---
  float mb = -3.0e38f;
#pragma unroll
  for (int t = 0; t < 4; ++t)
#pragma unroll
    for (int r = 0; r < 4; ++r) mb = fmaxf(mb, sc[t][r]);
  mb = fmaxf(mb, __shfl_xor(mb, 16, 64));
  mb = fmaxf(mb, __shfl_xor(mb, 32, 64));
  const float mnew = fmaxf(m_i, mb);
  const float alpha = __expf(m_i - mnew);
  m_i = mnew;
  float rs = 0.f;
#pragma unroll
  for (int t = 0; t < 4; ++t) {
    float p0 = __expf(sc[t][0] - mnew);
    float p1 = __expf(sc[t][1] - mnew);
    float p2 = __expf(sc[t][2] - mnew);
    float p3 = __expf(sc[t][3] - mnew);
    rs += (p0 + p1) + (p2 + p3);
    __hip_bfloat162 pk01 = __float22bfloat162_rn(make_float2(p0, p1));
    __hip_bfloat162 pk23 = __float22bfloat162_rn(make_float2(p2, p3));
    __hip_bfloat162* pd = (__hip_bfloat162*)(Psw + lr * PSP + t * 16 + quad * 4);
    pd[0] = pk01;
    pd[1] = pk23;
  }
  rs += __shfl_xor(rs, 16, 64);
  rs += __shfl_xor(rs, 32, 64);
  l_i = l_i * alpha + rs;
#pragma unroll
  for (int n = 0; n < 8; ++n)
#pragma unroll
    for (int r = 0; r < 4; ++r) o[n][r] *= alpha;
  // --- PV (K=32): P B-frags from wave-private LDS, V A-frags from shared LDS ---
  short8 pb0 = *(const short8*)(Psw + lr * PSP + quad * 8);
#pragma unroll
  for (int dt = 0; dt < 8; ++dt) {
    short8 vf = *(const short8*)(Vs + dt * 512 + lane_off);
    o[dt] = __builtin_amdgcn_mfma_f32_16x16x32_bf16(vf, pb0, o[dt], 0, 0, 0);
  }
  if (!MASK || nt > 2) {
    short8 pb1 = *(const short8*)(Psw + lr * PSP + 32 + quad * 8);
#pragma unroll
    for (int dt = 0; dt < 8; ++dt) {
      short8 vf = *(const short8*)(Vs + 4096 + dt * 512 + lane_off);
      o[dt] = __builtin_amdgcn_mfma_f32_16x16x32_bf16(vf, pb1, o[dt], 0, 0, 0);
    }
  }
}

__global__ __launch_bounds__(256) void attn_kernel(const short* __restrict__ Qb,
    const short* __restrict__ Kpack, const short* __restrict__ Vpack,
    short* __restrict__ Ob) {
  __shared__ alignas(16) short Ks[64 * HD];      // 16KB, Kpack frag-linear order
  __shared__ alignas(16) short Vs[64 * HD];      // 16KB, Vpack frag-linear order
  __shared__ alignas(16) short Ps[4][16 * PSP];
  const int tid = threadIdx.x, wave = tid >> 6, lane = tid & 63;
  const int quad = lane >> 4, lr = lane & 15;
  const int bid = blockIdx.x;
  const int sid  = bid & 7;           // (b,kvh) stream -> XCD L2 affinity
  const int hsub = (bid >> 3) & 3;
  const int qg   = 31 - (bid >> 5);   // heavy q-groups dispatched first
  const int b = sid >> 2, kvh = sid & 3;
  const int h = kvh * 4 + hsub;
  const int qw = (qg * 4 + wave) * 16;

  const short* Qp  = Qb    + ((size_t)(b * NH + h) * S_LEN + qw) * HD;
  const short* Kpk = Kpack + (size_t)(b * NKV + kvh) * S_LEN * HD;
  const short* Vpk = Vpack + (size_t)(b * NKV + kvh) * HD * S_LEN;
  short* Psw = &Ps[wave][0];

  // Q B-fragments (n=q=lr, k=d), loaded once
  short8 qf[4];
#pragma unroll
  for (int c = 0; c < 4; ++c)
    qf[c] = *(const short8*)(Qp + lr * HD + c * 32 + quad * 8);

  f32x4 o[8];
#pragma unroll
  for (int n = 0; n < 8; ++n) o[n] = (f32x4){0.f, 0.f, 0.f, 0.f};
  float m_i = -3.0e38f, l_i = 0.f;

  const int qlim = qw + lr;
  // uniform per-block loop: iters 0..qg-1 full, iter qg = per-wave masked tail
  for (int it = 0; it <= qg; ++it) {
    const int kv0 = it * 64;
    __syncthreads();   // previous iteration's LDS reads complete
    {
      const short* gk = Kpk + (size_t)kv0 * HD;          // tile-linear: 64kv = 16KB
      const short* gv = Vpk + (size_t)(kv0 >> 5) * 4096; // 2 chunks = 16KB
#pragma unroll
      for (int k = 0; k < 4; ++k) {
        const int off = (wave * 4 + k) * 512;            // shorts; 1KB per async16
        async16(gk + off + lane * 8, Ks + off);
        async16(gv + off + lane * 8, Vs + off);
      }
    }
    __syncthreads();   // drains vmcnt for global_load_lds
    if (it < qg)
      attn_iter64<false>(Ks, Vs, Psw, qf, kv0, 4, qlim, quad, lr, lane, o, m_i, l_i);
    else
      attn_iter64<true>(Ks, Vs, Psw, qf, kv0, wave + 1, qlim, quad, lr, lane, o, m_i, l_i);
  }

  // epilogue: lane holds O^T[d = dt*16+quad*4+r][q = qw+lr]
  const float invl = 1.0f / l_i;
  short* op = Ob + ((size_t)(qw + lr) * B_SZ + b) * D_MODEL + h * HD + quad * 4;
#pragma unroll
  for (int dt = 0; dt < 8; ++dt) {
    short4 ov;
    ov.x = f2bf(o[dt][0] * invl);
    ov.y = f2bf(o[dt][1] * invl);
    ov.z = f2bf(o[dt][2] * invl);
    ov.w = f2bf(o[dt][3] * invl);
    *(short4*)(op + dt * 16) = ov;
  }
}

// ---------------- launch ----------------
extern "C" void kernel_launch(void* const* d_in, const int* in_sizes, int n_in,
                              void* d_out, int out_size, void* d_ws, size_t ws_size,
                              hipStream_t stream) {
  (void)in_sizes; (void)n_in; (void)out_size; (void)ws_size;
  const float* x  = (const float*)d_in[0];
  const float* Wq = (const float*)d_in[1];
  const float* Wk = (const float*)d_in[2];
  const float* Wv = (const float*)d_in[3];
  const float* Wo = (const float*)d_in[4];
  float* out = (float*)d_out;
  char* ws = (char*)d_ws;

  // region A [0, 29360128): Wqkv_t(12M)+xb(16M); later Qb(16M)+Kpack(4M)+Vpack(4M)
  short* Wqkv_t = (short*)(ws);                    // [3072][2048]
  short* xb     = (short*)(ws + 12582912);         // [4096][2048]
  short* Qb     = (short*)(ws);                    // [2][16][2048][128]
  short* Kpack  = (short*)(ws + 16777216);         // packed K frags, 4MB
  short* Vpack  = (short*)(ws + 25165824);         // packed V^T frags, 4MB
  // region B [29360128, 54525952): QKVb(24M); later Ob(16M)
  short* QKVb   = (short*)(ws + 29360128);         // [4096][3072]
  short* Ob     = (short*)(ws + 29360128);         // [4096][2048]
  // region C [54525952, 62914560): Wo_t(8M)
  short* Wo_t   = (short*)(ws + 54525952);         // [2048][2048]

  dim3 tblk(32, 8);

  // 1. x -> bf16
  cvt_bf16_kernel<<<(ROWS * D_MODEL / 4 + 255) / 256, 256, 0, stream>>>(x, xb, ROWS * D_MODEL / 4);
  // 2. weight transposes to B^T layout (bf16); Wq/Wk/Wv merged
  wtrans_qkv_kernel<<<dim3(96, 64), tblk, 0, stream>>>(Wq, Wk, Wv, Wqkv_t);
  wtrans_kernel<<<dim3(64, 64), tblk, 0, stream>>>(Wo, Wo_t, 2048, 2048);
  // 3. QKV projection (bf16 out)
  gemm_bt_kernel<1><<<dim3(NQKV / BN, ROWS / BM), 256, 0, stream>>>(xb, Wqkv_t, QKVb, ROWS, NQKV, D_MODEL);
  // 4. RoPE: Q -> Qb, K -> packed frags
  rope_kernel<<<dim3(1024, NH + NKV), 256, 0, stream>>>(QKVb, Qb, Kpack);
  // 5. fused V pack (QKVb -> PV A-operand layout)
  vpack_kernel<<<dim3(512), 256, 0, stream>>>(QKVb, Vpack);
  // 6. causal flash attention (block-shared LDS staging, 4 waves/stream)
  attn_kernel<<<dim3(1024), 256, 0, stream>>>(Qb, Kpack, Vpack, Ob);
  // 7. output projection (fp32 out)
  gemm_bt_kernel<0><<<dim3(D_MODEL / BN, ROWS / BM), 256, 0, stream>>>(Ob, Wo_t, out, ROWS, D_MODEL, D_MODEL);
}